// Round 2
// baseline (887.215 us; speedup 1.0000x reference)
//
#include <hip/hip_runtime.h>

// PAU (Padé Activation Unit), version A:
//   z = x + center
//   P(z) = a0 + a1 z + ... + a5 z^5          (Horner)
//   Q(z) = 1 + |z|*(|b1| + |z|*(|b2| + |z|*(|b3| + |z|*|b4|)))
//   out = P / Q
//
// Elementwise, memory-bound: 1.073 GB traffic -> ~170 us floor at 6.3 TB/s.
//
// R2 = R1 with compile fix:
//  - __builtin_nontemporal_load/store requires a NATIVE vector type, not
//    HIP's float4 class. Use ext_vector_type(4) (same 16B layout).
//  - grid-stride, grid capped at 2048 blocks (8/CU), 4-deep hand unroll.
//  - p/q via v_rcp_f32 + mul (q >= 1 always; ~1 ulp << absmax tol 0.015625).

typedef float floatx4 __attribute__((ext_vector_type(4)));

__device__ __forceinline__ float pau_eval(
    float xv, float c,
    float a0, float a1, float a2, float a3, float a4, float a5,
    float b1, float b2, float b3, float b4)
{
    const float z = xv + c;
    // numerator Horner
    float p = fmaf(a5, z, a4);
    p = fmaf(p, z, a3);
    p = fmaf(p, z, a2);
    p = fmaf(p, z, a1);
    p = fmaf(p, z, a0);
    // denominator Horner on |z|
    const float az = fabsf(z);
    float q = fmaf(b4, az, b3);
    q = fmaf(q, az, b2);
    q = fmaf(q, az, b1);
    q = fmaf(q, az, 1.0f);           // q >= 1: rcp is safe
    return p * __builtin_amdgcn_rcpf(q);
}

__device__ __forceinline__ floatx4 pau_eval4(
    floatx4 v, float c,
    float a0, float a1, float a2, float a3, float a4, float a5,
    float b1, float b2, float b3, float b4)
{
    floatx4 r;
    r.x = pau_eval(v.x, c, a0,a1,a2,a3,a4,a5, b1,b2,b3,b4);
    r.y = pau_eval(v.y, c, a0,a1,a2,a3,a4,a5, b1,b2,b3,b4);
    r.z = pau_eval(v.z, c, a0,a1,a2,a3,a4,a5, b1,b2,b3,b4);
    r.w = pau_eval(v.w, c, a0,a1,a2,a3,a4,a5, b1,b2,b3,b4);
    return r;
}

__global__ __launch_bounds__(256) void PAU_kernel(
    const float* __restrict__ x,
    const float* __restrict__ center,
    const float* __restrict__ num,   // 6 coeffs a0..a5
    const float* __restrict__ den,   // 4 coeffs b1..b4
    float* __restrict__ out,
    long long n4,                    // number of float4 vectors
    long long n)                     // total elements
{
    // Uniform scalar loads (same address across wave -> s_load, cached).
    const float c  = center[0];
    const float a0 = num[0], a1 = num[1], a2 = num[2],
                a3 = num[3], a4 = num[4], a5 = num[5];
    const float b1 = fabsf(den[0]), b2 = fabsf(den[1]),
                b3 = fabsf(den[2]), b4 = fabsf(den[3]);

    const long long S = (long long)gridDim.x * blockDim.x;  // total threads
    long long i = (long long)blockIdx.x * blockDim.x + threadIdx.x;

    const floatx4* __restrict__ xin  = reinterpret_cast<const floatx4*>(x);
    floatx4* __restrict__       yout = reinterpret_cast<floatx4*>(out);

    // Main loop: 4 independent float4 streams in flight.
    for (; i + 3 * S < n4; i += 4 * S) {
        floatx4 v0 = __builtin_nontemporal_load(xin + i);
        floatx4 v1 = __builtin_nontemporal_load(xin + i + S);
        floatx4 v2 = __builtin_nontemporal_load(xin + i + 2 * S);
        floatx4 v3 = __builtin_nontemporal_load(xin + i + 3 * S);

        floatx4 r0 = pau_eval4(v0, c, a0,a1,a2,a3,a4,a5, b1,b2,b3,b4);
        floatx4 r1 = pau_eval4(v1, c, a0,a1,a2,a3,a4,a5, b1,b2,b3,b4);
        floatx4 r2 = pau_eval4(v2, c, a0,a1,a2,a3,a4,a5, b1,b2,b3,b4);
        floatx4 r3 = pau_eval4(v3, c, a0,a1,a2,a3,a4,a5, b1,b2,b3,b4);

        __builtin_nontemporal_store(r0, yout + i);
        __builtin_nontemporal_store(r1, yout + i + S);
        __builtin_nontemporal_store(r2, yout + i + 2 * S);
        __builtin_nontemporal_store(r3, yout + i + 3 * S);
    }

    // Remainder float4s.
    for (; i < n4; i += S) {
        floatx4 v = __builtin_nontemporal_load(xin + i);
        floatx4 r = pau_eval4(v, c, a0,a1,a2,a3,a4,a5, b1,b2,b3,b4);
        __builtin_nontemporal_store(r, yout + i);
    }

    // Scalar tail (n not divisible by 4). Dead for this problem (n % 4 == 0),
    // kept for safety.
    if (blockIdx.x == 0 && threadIdx.x == 0) {
        for (long long t = n4 * 4; t < n; ++t) {
            out[t] = pau_eval(x[t], c, a0,a1,a2,a3,a4,a5, b1,b2,b3,b4);
        }
    }
}

extern "C" void kernel_launch(void* const* d_in, const int* in_sizes, int n_in,
                              void* d_out, int out_size, void* d_ws, size_t ws_size,
                              hipStream_t stream) {
    const float* x      = (const float*)d_in[0];
    const float* center = (const float*)d_in[1];
    const float* num    = (const float*)d_in[2];
    const float* den    = (const float*)d_in[3];
    float* out          = (float*)d_out;

    const long long n  = (long long)in_sizes[0];
    const long long n4 = n / 4;

    const int block = 256;
    long long grid = (n4 + block - 1) / block;
    if (grid > 2048) grid = 2048;   // 8 blocks/CU on 256 CUs; grid-stride the rest
    if (grid < 1) grid = 1;

    PAU_kernel<<<(unsigned)grid, block, 0, stream>>>(x, center, num, den, out, n4, n);
}

// Round 3
// 812.691 us; speedup vs baseline: 1.0917x; 1.0917x over previous
//
#include <hip/hip_runtime.h>

// PAU (Padé Activation Unit), version A:
//   z = x + center
//   P(z) = a0 + a1 z + ... + a5 z^5          (Horner)
//   Q(z) = 1 + |z|*(|b1| + |z|*(|b2| + |z|*(|b3| + |z|*|b4|)))
//   out = P / Q
//
// Elementwise, memory-bound: 1.073 GB traffic -> ~170 us floor at 6.3 TB/s.
//
// R3 = revert to the harness-verified R0 streaming structure (flat index,
// one float4 per thread, NORMAL cached loads/stores — R2's nontemporal
// stores regressed the bench by ~78 us, most plausibly by defeating L2
// write-combining), keeping one safe micro-change:
//  - p/q via v_rcp_f32 + mul instead of the precise-div sequence.
//    q >= 1 always (1 + sum of non-negative terms), so rcp is
//    well-conditioned; ~1 ulp error << absmax tol 0.015625.
//    VALU arithmetic: ~38 us of chip-wide VALU vs ~180 us memory floor,
//    so this is timing-neutral; it only shortens the dependent chain.

__global__ __launch_bounds__(256) void PAU_kernel(
    const float* __restrict__ x,
    const float* __restrict__ center,
    const float* __restrict__ num,   // 6 coeffs a0..a5
    const float* __restrict__ den,   // 4 coeffs b1..b4
    float* __restrict__ out,
    long long n4,                    // number of float4 vectors
    long long n)                     // total elements
{
    // Uniform scalar loads (same address across wave -> s_load, cached).
    const float c  = center[0];
    const float a0 = num[0], a1 = num[1], a2 = num[2],
                a3 = num[3], a4 = num[4], a5 = num[5];
    const float b1 = fabsf(den[0]), b2 = fabsf(den[1]),
                b3 = fabsf(den[2]), b4 = fabsf(den[3]);

    const long long i = (long long)blockIdx.x * blockDim.x + threadIdx.x;

    if (i < n4) {
        float4 v = reinterpret_cast<const float4*>(x)[i];
        float4 r;
        const float* vp = &v.x;
        float* rp = &r.x;
#pragma unroll
        for (int k = 0; k < 4; ++k) {
            const float z = vp[k] + c;
            // numerator Horner
            float p = fmaf(a5, z, a4);
            p = fmaf(p, z, a3);
            p = fmaf(p, z, a2);
            p = fmaf(p, z, a1);
            p = fmaf(p, z, a0);
            // denominator Horner on |z|
            const float az = fabsf(z);
            float q = fmaf(b4, az, b3);
            q = fmaf(q, az, b2);
            q = fmaf(q, az, b1);
            q = fmaf(q, az, 1.0f);               // q >= 1: rcp is safe
            rp[k] = p * __builtin_amdgcn_rcpf(q);
        }
        reinterpret_cast<float4*>(out)[i] = r;
    }

    // Scalar tail (n not divisible by 4). Dead for this problem (n % 4 == 0),
    // kept for safety.
    if (i == 0) {
        for (long long t = n4 * 4; t < n; ++t) {
            const float z = x[t] + c;
            float p = fmaf(a5, z, a4);
            p = fmaf(p, z, a3);
            p = fmaf(p, z, a2);
            p = fmaf(p, z, a1);
            p = fmaf(p, z, a0);
            const float az = fabsf(z);
            float q = fmaf(b4, az, b3);
            q = fmaf(q, az, b2);
            q = fmaf(q, az, b1);
            q = fmaf(q, az, 1.0f);
            out[t] = p * __builtin_amdgcn_rcpf(q);
        }
    }
}

extern "C" void kernel_launch(void* const* d_in, const int* in_sizes, int n_in,
                              void* d_out, int out_size, void* d_ws, size_t ws_size,
                              hipStream_t stream) {
    const float* x      = (const float*)d_in[0];
    const float* center = (const float*)d_in[1];
    const float* num    = (const float*)d_in[2];
    const float* den    = (const float*)d_in[3];
    float* out          = (float*)d_out;

    const long long n  = (long long)in_sizes[0];
    const long long n4 = n / 4;

    const int block = 256;
    const long long grid = (n4 + block - 1) / block;

    PAU_kernel<<<(unsigned)grid, block, 0, stream>>>(x, center, num, den, out, n4, n);
}